// Round 13
// baseline (525.719 us; speedup 1.0000x reference)
//
#include <hip/hip_runtime.h>
#include <math.h>

#define H 128
#define NG 8

typedef __attribute__((ext_vector_type(8))) short bf16x8;
typedef __attribute__((ext_vector_type(8))) unsigned short ushort8;
typedef __attribute__((ext_vector_type(4))) float f32x4;

static __device__ __forceinline__ float b2f(unsigned short u) {
  union { unsigned int i; float f; } v;
  v.i = ((unsigned int)u) << 16;
  return v.f;
}
static __device__ __forceinline__ unsigned short f2b(float f) {
  return (unsigned short)(__float_as_uint(f) >> 16);  // truncation; exact for small ints
}

// ---------------- CSR build ----------------
__global__ void k_hist(const int* __restrict__ ei, int E, int* __restrict__ cnt) {
  int e = blockIdx.x * 256 + threadIdx.x;
  if (e >= E) return;
  atomicAdd(&cnt[ei[E + e]], 1);
}

// scan + dv0 = rsqrt(cnt+2) fused
__global__ __launch_bounds__(1024) void k_scan(const int* __restrict__ cnt,
                                               int* __restrict__ rowptr,
                                               float* __restrict__ dv, int n) {
  __shared__ int sums[1024];
  int tid = threadIdx.x;
  int base = tid * 4;
  int v0 = 0, v1 = 0, v2 = 0, v3 = 0;
  if (base < n) { v0 = cnt[base]; v1 = cnt[base + 1]; v2 = cnt[base + 2]; v3 = cnt[base + 3]; }
  int s = v0 + v1 + v2 + v3;
  sums[tid] = s;
  __syncthreads();
  for (int off = 1; off < 1024; off <<= 1) {
    int t = (tid >= off) ? sums[tid - off] : 0;
    __syncthreads();
    sums[tid] += t;
    __syncthreads();
  }
  int excl = sums[tid] - s;
  if (base < n) {
    rowptr[base] = excl;
    rowptr[base + 1] = excl + v0;
    rowptr[base + 2] = excl + v0 + v1;
    rowptr[base + 3] = excl + v0 + v1 + v2;
    dv[base] = rsqrtf((float)v0 + 2.0f);
    dv[base + 1] = rsqrtf((float)v1 + 2.0f);
    dv[base + 2] = rsqrtf((float)v2 + 2.0f);
    dv[base + 3] = rsqrtf((float)v3 + 2.0f);
  }
  if (tid == 1023) rowptr[n] = sums[1023];
}

__global__ void k_fill(const int* __restrict__ ei, int E, const int* __restrict__ rowptr,
                       int* __restrict__ cursor, int* __restrict__ colidx) {
  int e = blockIdx.x * 256 + threadIdx.x;
  if (e >= E) return;
  int r = ei[E + e], c = ei[e];
  int p = atomicAdd(&cursor[r], 1);
  colidx[rowptr[r] + p] = c;
}

// Y[r,c] = d(r) * sum_k X'[r,k] W[k,c]; RS: dv holds rowsum; EMIT: also write YT bf16 hi/lo limbs
// MODE 0: X'=X ; 1 (pool): X[perm[r]]*score ; 2 (skip): X[r]+prev[inv[r]]
template <int MODE, int RS, int EMIT>
__global__ __launch_bounds__(256) void k_xw(const float* __restrict__ X,
                                            const float* __restrict__ W,
                                            const float* __restrict__ dv,
                                            const int* __restrict__ idx,
                                            const float* __restrict__ aux,
                                            float* __restrict__ Y,
                                            unsigned short* __restrict__ YT,
                                            int n, int F) {
  __shared__ float Xs[64][36];
  __shared__ float Ws[32][132];
  __shared__ int ridx[64];
  __shared__ float rscl[64];
  int tid = threadIdx.x;
  int rowBase = blockIdx.x * 64;
  if (MODE == 1) {
    if (tid < 64) {
      int pp = idx[rowBase + tid];
      ridx[tid] = pp;
      rscl[tid] = aux[pp];
    }
  } else if (MODE == 2) {
    if (tid < 64) ridx[tid] = idx[rowBase + tid];
  }
  if (MODE != 0) __syncthreads();
  int r0 = (tid >> 5) << 3;
  int c0 = (tid & 31) << 2;
  float acc[8][4] = {};
  for (int k0 = 0; k0 < F; k0 += 32) {
#pragma unroll
    for (int it = 0, e = tid; it < 8; ++it, e += 256) {
      int ii = e >> 5, kk = e & 31;
      int gk = k0 + kk;
      float v;
      if (MODE == 0) {
        v = X[(size_t)(rowBase + ii) * F + gk];
      } else if (MODE == 1) {
        v = X[(size_t)ridx[ii] * F + gk] * rscl[ii];
      } else {
        v = X[(size_t)(rowBase + ii) * F + gk];
        int iv = ridx[ii];
        if (iv >= 0) v += aux[(size_t)iv * H + gk];
      }
      Xs[ii][kk] = v;
    }
#pragma unroll
    for (int it = 0, e = tid; it < 4; ++it, e += 256) {
      int kk = e >> 5, cc4 = e & 31;
      *(float4*)&Ws[kk][cc4 << 2] = *(const float4*)&W[(size_t)(k0 + kk) * H + (cc4 << 2)];
    }
    __syncthreads();
#pragma unroll
    for (int kk = 0; kk < 32; kk += 4) {
      float4 a4[8], w4[4];
#pragma unroll
      for (int i = 0; i < 8; ++i) a4[i] = *(const float4*)&Xs[r0 + i][kk];
#pragma unroll
      for (int s = 0; s < 4; ++s) w4[s] = *(const float4*)&Ws[kk + s][c0];
#pragma unroll
      for (int i = 0; i < 8; ++i) {
        float av[4] = {a4[i].x, a4[i].y, a4[i].z, a4[i].w};
#pragma unroll
        for (int s = 0; s < 4; ++s) {
          float wv[4] = {w4[s].x, w4[s].y, w4[s].z, w4[s].w};
#pragma unroll
          for (int j = 0; j < 4; ++j) acc[i][j] = fmaf(av[s], wv[j], acc[i][j]);
        }
      }
    }
    __syncthreads();
  }
  float vout[8][4];
#pragma unroll
  for (int i = 0; i < 8; ++i) {
    int row = rowBase + r0 + i;
    float d = RS ? rsqrtf(dv[row] + 2.0f) : dv[row];
#pragma unroll
    for (int j = 0; j < 4; ++j) vout[i][j] = d * acc[i][j];
    *(float4*)&Y[(size_t)row * H + c0] =
        make_float4(vout[i][0], vout[i][1], vout[i][2], vout[i][3]);
  }
  if (EMIT) {
#pragma unroll
    for (int j = 0; j < 4; ++j) {
      ushort8 hi, lo;
#pragma unroll
      for (int i = 0; i < 8; ++i) {
        float v = vout[i][j];
        unsigned short hh = f2b(v);
        hi[i] = hh;
        lo[i] = f2b(v - b2f(hh));
      }
      int c = c0 + j;
      *(ushort8*)&YT[(size_t)c * (2 * n) + rowBase + r0] = hi;
      *(ushort8*)&YT[(size_t)c * (2 * n) + n + rowBase + r0] = lo;
    }
  }
}

// sparse GCN epilogue; lane covers cols 2*lane, 2*lane+1. SCORE: emit tanh((out@w)/||w||)
template <int SCORE>
__global__ void k_spmm_fin(const int* __restrict__ rowptr, const int* __restrict__ colidx,
                           const float* __restrict__ Y, const float* __restrict__ dv,
                           const float* __restrict__ bias, float* __restrict__ Out,
                           const float* __restrict__ w, float* __restrict__ score,
                           int n, int relu) {
  __shared__ float wn;
  int tid = threadIdx.x;
  if (SCORE) {
    if (tid < 64) {
      float s = w[tid] * w[tid] + w[tid + 64] * w[tid + 64];
#pragma unroll
      for (int o = 32; o > 0; o >>= 1) s += __shfl_down(s, o);
      if (tid == 0) wn = sqrtf(s);
    }
    __syncthreads();
  }
  int row = blockIdx.x * 4 + (tid >> 6);
  int lane = tid & 63;
  if (row >= n) return;
  int s = rowptr[row], e = rowptr[row + 1];
  int c2 = lane * 2;
  float a0 = 0.f, a1 = 0.f;
  int i = s;
  for (; i + 1 < e; i += 2) {
    int cA = colidx[i], cB = colidx[i + 1];
    float2 yA = *(const float2*)&Y[(size_t)cA * H + c2];
    float2 yB = *(const float2*)&Y[(size_t)cB * H + c2];
    a0 += yA.x + yB.x;
    a1 += yA.y + yB.y;
  }
  if (i < e) {
    int c = colidx[i];
    float2 y = *(const float2*)&Y[(size_t)c * H + c2];
    a0 += y.x;
    a1 += y.y;
  }
  float d = dv[row];
  float2 yr = *(const float2*)&Y[(size_t)row * H + c2];
  float v0 = d * (a0 + 2.0f * yr.x) + bias[c2];
  float v1 = d * (a1 + 2.0f * yr.y) + bias[c2 + 1];
  if (relu) { v0 = fmaxf(v0, 0.f); v1 = fmaxf(v1, 0.f); }
  *(float2*)&Out[(size_t)row * H + c2] = make_float2(v0, v1);
  if (SCORE) {
    float sc = v0 * w[c2] + v1 * w[c2 + 1];
#pragma unroll
    for (int o = 32; o > 0; o >>= 1) sc += __shfl_down(sc, o);
    if (lane == 0) score[row] = tanhf(sc / wn);
  }
}

// level-0 ATA, row-wise (LDS int accumulators) -> bf16 row + dv fused
__global__ __launch_bounds__(256) void k_ata_rows(const int* __restrict__ rowptr,
                                                  const int* __restrict__ colidx,
                                                  const int* __restrict__ perm,
                                                  const int* __restrict__ inv,
                                                  unsigned short* __restrict__ Ab,
                                                  float* __restrict__ dv, int kdim) {
  __shared__ int acc[2048];
  __shared__ int wsum[4];
  int i = blockIdx.x;
  int tid = threadIdx.x;
  for (int j = tid; j < kdim; j += 256) acc[j] = 0;
  __syncthreads();
  int p = perm[i];
  int s = rowptr[p], e = rowptr[p + 1];
  int deg = e - s;
  int wave = tid >> 6, lane = tid & 63;
  for (int q = wave; q <= deg; q += 4) {
    int kn = (q < deg) ? colidx[s + q] : p;
    int s2 = rowptr[kn], e2 = rowptr[kn + 1];
    for (int idx = s2 + lane; idx <= e2; idx += 64) {
      int j = (idx < e2) ? colidx[idx] : kn;
      int ii = inv[j];
      if (ii >= 0) atomicAdd(&acc[ii], 1);
    }
  }
  __syncthreads();
  int rs = 0;
  {
    int j0 = tid * 8;
    ushort8 v;
#pragma unroll
    for (int q = 0; q < 8; ++q) {
      int j = j0 + q;
      int c = (j == i) ? 0 : acc[j];
      rs += c;
      v[q] = f2b((float)c);
    }
    *(ushort8*)&Ab[(size_t)i * kdim + j0] = v;
  }
#pragma unroll
  for (int o = 32; o > 0; o >>= 1) rs += __shfl_down(rs, o);
  if (lane == 0) wsum[wave] = rs;
  __syncthreads();
  if (tid == 0) dv[i] = rsqrtf((float)(wsum[0] + wsum[1] + wsum[2] + wsum[3]) + 2.0f);
}

// level-1 ATA partial: bf16 MFMA (gather + +I fused), z-chunk private partial
__global__ __launch_bounds__(256) void k_ata_mfma_g(const unsigned short* __restrict__ Ab,
                                                    const int* __restrict__ perm,
                                                    float* __restrict__ PartC,
                                                    int n, int k, int KC) {
  __shared__ __align__(16) unsigned short As[64][64];
  __shared__ __align__(16) unsigned short Bs[64][64];
  __shared__ int pr[64], pc[64];
  int tid = threadIdx.x;
  int w = tid >> 6, ln = tid & 63;
  int l15 = ln & 15, l4 = ln >> 4;
  int br = blockIdx.y, bc = blockIdx.x;
  if (tid < 64) pr[tid] = perm[br * 64 + tid];
  else if (tid < 128) pc[tid - 64] = perm[bc * 64 + (tid - 64)];
  __syncthreads();
  f32x4 acc[4] = {};
  int k0s = blockIdx.z * KC;
  for (int k0 = k0s; k0 < k0s + KC; k0 += 64) {
#pragma unroll
    for (int it = 0; it < 2; ++it) {
      int e = tid + it * 256;
      int row = e >> 3, ch = e & 7;
      int sch = (ch ^ (row & 7)) * 8;
      int base = k0 + ch * 8;
      {
        int p = pr[row];
        ushort8 v = *(const ushort8*)&Ab[(size_t)p * n + base];
#pragma unroll
        for (int q = 0; q < 8; ++q)
          if (base + q == p) v[q] = f2b(b2f(v[q]) + 1.0f);
        *(ushort8*)&As[row][sch] = v;
      }
      {
        int p = pc[row];
        ushort8 v = *(const ushort8*)&Ab[(size_t)p * n + base];
#pragma unroll
        for (int q = 0; q < 8; ++q)
          if (base + q == p) v[q] = f2b(b2f(v[q]) + 1.0f);
        *(ushort8*)&Bs[row][sch] = v;
      }
    }
    __syncthreads();
#pragma unroll
    for (int s = 0; s < 2; ++s) {
      int arow = w * 16 + l15;
      bf16x8 af = *(const bf16x8*)&As[arow][((s * 4 + l4) ^ (arow & 7)) * 8];
#pragma unroll
      for (int f = 0; f < 4; ++f) {
        int brow = f * 16 + l15;
        bf16x8 bfr = *(const bf16x8*)&Bs[brow][((s * 4 + l4) ^ (brow & 7)) * 8];
        acc[f] = __builtin_amdgcn_mfma_f32_16x16x32_bf16(af, bfr, acc[f], 0, 0, 0);
      }
    }
    __syncthreads();
  }
  float* out = PartC + (size_t)blockIdx.z * k * k;
#pragma unroll
  for (int f = 0; f < 4; ++f) {
#pragma unroll
    for (int r = 0; r < 4; ++r) {
      int gi = br * 64 + w * 16 + l4 * 4 + r;
      int gj = bc * 64 + f * 16 + l15;
      out[(size_t)gi * k + gj] = acc[f][r];
    }
  }
}

// level-2 ATA partial: fp32, gather + +I, z-chunk private partial (no atomics)
__global__ __launch_bounds__(256) void k_ata_sk_part(const float* __restrict__ A,
                                                     const int* __restrict__ perm,
                                                     float* __restrict__ PartC,
                                                     int n, int k, int CK) {
  int bc = blockIdx.x, br = blockIdx.y;
  __shared__ float As[64][36];
  __shared__ float Bs[64][36];
  __shared__ int pr[64], pc[64];
  int tid = threadIdx.x;
  if (tid < 64) pr[tid] = perm[br * 64 + tid];
  else if (tid < 128) pc[tid - 64] = perm[bc * 64 + (tid - 64)];
  __syncthreads();
  int ty = tid >> 4;
  int tx = tid & 15;
  float acc[4][4] = {};
  int k0s = blockIdx.z * CK;
  for (int k0 = k0s; k0 < k0s + CK; k0 += 32) {
#pragma unroll
    for (int it = 0, e = tid; it < 8; ++it, e += 256) {
      int ii = e >> 5, kk = e & 31;
      int gk = k0 + kk;
      int p = pr[ii];
      As[ii][kk] = A[(size_t)p * n + gk] + ((p == gk) ? 1.0f : 0.0f);
      p = pc[ii];
      Bs[ii][kk] = A[(size_t)p * n + gk] + ((p == gk) ? 1.0f : 0.0f);
    }
    __syncthreads();
#pragma unroll
    for (int kk = 0; kk < 32; kk += 4) {
      float4 a4[4], b4[4];
#pragma unroll
      for (int i = 0; i < 4; ++i) a4[i] = *(const float4*)&As[ty + 16 * i][kk];
#pragma unroll
      for (int j = 0; j < 4; ++j) b4[j] = *(const float4*)&Bs[tx + 16 * j][kk];
#pragma unroll
      for (int i = 0; i < 4; ++i) {
        float av[4] = {a4[i].x, a4[i].y, a4[i].z, a4[i].w};
#pragma unroll
        for (int j = 0; j < 4; ++j) {
          float bv[4] = {b4[j].x, b4[j].y, b4[j].z, b4[j].w};
#pragma unroll
          for (int s = 0; s < 4; ++s) acc[i][j] = fmaf(av[s], bv[s], acc[i][j]);
        }
      }
    }
    __syncthreads();
  }
  float* out = PartC + (size_t)blockIdx.z * k * k;
#pragma unroll
  for (int i = 0; i < 4; ++i) {
    int gi = br * 64 + ty + 16 * i;
#pragma unroll
    for (int j = 0; j < 4; ++j) {
      int gj = bc * 64 + tx + 16 * j;
      out[(size_t)gi * k + gj] = acc[i][j];
    }
  }
}

// sum NCH ATA partials, zero diag, write C, emit raw rowsum. blockDim = k/4.
template <int NCH>
__global__ void k_ata_fin(const float* __restrict__ PartC, float* __restrict__ C,
                          float* __restrict__ rowsum, int k) {
  __shared__ float wsum[4];
  int gi = blockIdx.x;
  int tid = threadIdx.x;
  int j4 = tid * 4;
  size_t stride = (size_t)k * k;
  size_t off = (size_t)gi * k + j4;
  float4 s = *(const float4*)&PartC[off];
#pragma unroll
  for (int z = 1; z < NCH; ++z) {
    float4 p = *(const float4*)&PartC[z * stride + off];
    s.x += p.x; s.y += p.y; s.z += p.z; s.w += p.w;
  }
  if (gi >= j4 && gi < j4 + 4) ((float*)&s)[gi - j4] = 0.0f;
  *(float4*)&C[off] = s;
  float part = s.x + s.y + s.z + s.w;
  int lane = tid & 63, wave = tid >> 6;
#pragma unroll
  for (int o = 32; o > 0; o >>= 1) part += __shfl_down(part, o);
  if (lane == 0) wsum[wave] = part;
  __syncthreads();
  if (tid == 0) {
    int nw = blockDim.x >> 6;
    float t = 0.f;
    for (int q = 0; q < nw; ++q) t += wsum[q];
    rowsum[gi] = t;
  }
}

// Partial A@Y via bf16 MFMA over virtual K=2n (hi|lo limbs). Split-K private partials.
__global__ __launch_bounds__(256) void k_gcn_mfma(const unsigned short* __restrict__ A,
                                                  const unsigned short* __restrict__ YT,
                                                  float* __restrict__ Part, int n, int VK) {
  __shared__ __align__(16) unsigned short As[64][64];
  __shared__ __align__(16) unsigned short Bs[128][64];
  int tid = threadIdx.x;
  int w = tid >> 6, ln = tid & 63;
  int l15 = ln & 15, l4 = ln >> 4;
  int rowBase = blockIdx.x * 64;
  float* out = Part + (size_t)blockIdx.y * n * H;
  f32x4 acc[8] = {};
  int vk0s = blockIdx.y * VK;
  for (int vk0 = vk0s; vk0 < vk0s + VK; vk0 += 64) {
    int ka = vk0 & (n - 1);
#pragma unroll
    for (int it = 0; it < 2; ++it) {
      int e = tid + it * 256;
      int row = e >> 3, ch = e & 7;
      int sch = (ch ^ (row & 7)) * 8;
      *(ushort8*)&As[row][sch] = *(const ushort8*)&A[(size_t)(rowBase + row) * n + ka + ch * 8];
    }
#pragma unroll
    for (int it = 0; it < 4; ++it) {
      int e = tid + it * 256;
      int row = e >> 3, ch = e & 7;
      int sch = (ch ^ (row & 7)) * 8;
      *(ushort8*)&Bs[row][sch] = *(const ushort8*)&YT[(size_t)row * (2 * n) + vk0 + ch * 8];
    }
    __syncthreads();
#pragma unroll
    for (int s = 0; s < 2; ++s) {
      int arow = w * 16 + l15;
      bf16x8 af = *(const bf16x8*)&As[arow][((s * 4 + l4) ^ (arow & 7)) * 8];
#pragma unroll
      for (int f = 0; f < 8; ++f) {
        int brow = f * 16 + l15;
        bf16x8 bfr = *(const bf16x8*)&Bs[brow][((s * 4 + l4) ^ (brow & 7)) * 8];
        acc[f] = __builtin_amdgcn_mfma_f32_16x16x32_bf16(af, bfr, acc[f], 0, 0, 0);
      }
    }
    __syncthreads();
  }
#pragma unroll
  for (int f = 0; f < 8; ++f) {
#pragma unroll
    for (int r = 0; r < 4; ++r) {
      int row = rowBase + w * 16 + l4 * 4 + r;
      out[(size_t)row * H + f * 16 + l15] = acc[f][r];
    }
  }
}

// fp32 dense GCN partial (split-K, private partials)
__global__ __launch_bounds__(256) void k_gcn_part(const float* __restrict__ A,
                                                  const float* __restrict__ Y,
                                                  float* __restrict__ Part,
                                                  int n, int KC) {
  __shared__ float As[64][36];
  __shared__ float Ys[32][132];
  int tid = threadIdx.x;
  int r0 = (tid >> 5) << 3;
  int c0 = (tid & 31) << 2;
  size_t rowBase = (size_t)blockIdx.x * 64;
  int k0s = blockIdx.y * KC;
  float* out = Part + (size_t)blockIdx.y * n * H;
  float acc[8][4] = {};
  for (int k0 = k0s; k0 < k0s + KC; k0 += 32) {
#pragma unroll
    for (int it = 0, e = tid; it < 8; ++it, e += 256) {
      int ii = e >> 5, kk = e & 31;
      As[ii][kk] = A[(rowBase + ii) * (size_t)n + k0 + kk];
    }
#pragma unroll
    for (int it = 0, e = tid; it < 4; ++it, e += 256) {
      int kk = e >> 5, cc4 = e & 31;
      *(float4*)&Ys[kk][cc4 << 2] = *(const float4*)&Y[(size_t)(k0 + kk) * H + (cc4 << 2)];
    }
    __syncthreads();
#pragma unroll
    for (int kk = 0; kk < 32; kk += 4) {
      float4 a4[8], y4[4];
#pragma unroll
      for (int i = 0; i < 8; ++i) a4[i] = *(const float4*)&As[r0 + i][kk];
#pragma unroll
      for (int s = 0; s < 4; ++s) y4[s] = *(const float4*)&Ys[kk + s][c0];
#pragma unroll
      for (int i = 0; i < 8; ++i) {
        float av[4] = {a4[i].x, a4[i].y, a4[i].z, a4[i].w};
#pragma unroll
        for (int s = 0; s < 4; ++s) {
          float yv[4] = {y4[s].x, y4[s].y, y4[s].z, y4[s].w};
#pragma unroll
          for (int j = 0; j < 4; ++j) acc[i][j] = fmaf(av[s], yv[j], acc[i][j]);
        }
      }
    }
    __syncthreads();
  }
#pragma unroll
  for (int i = 0; i < 8; ++i) {
    size_t row = rowBase + r0 + i;
    *(float4*)&out[row * H + c0] = make_float4(acc[i][0], acc[i][1], acc[i][2], acc[i][3]);
  }
}

// Out = act(d .* (sum Part + 2Y) + bias); RS: dv holds rowsum; SCORE: emit score
template <int RS, int SCORE>
__global__ void k_gcn_fin(const float* __restrict__ Part, const float* __restrict__ Y,
                          const float* __restrict__ dv, const float* __restrict__ bias,
                          float* __restrict__ Out,
                          const float* __restrict__ w, float* __restrict__ score,
                          int n, int nch, int relu) {
  __shared__ float wn;
  int tid = threadIdx.x;
  if (SCORE) {
    if (tid < 64) {
      float s = w[tid] * w[tid] + w[tid + 64] * w[tid + 64];
#pragma unroll
      for (int o = 32; o > 0; o >>= 1) s += __shfl_down(s, o);
      if (tid == 0) wn = sqrtf(s);
    }
    __syncthreads();
  }
  int i4 = blockIdx.x * 256 + tid;
  int row = i4 >> 5, c4 = (i4 & 31) * 4;
  size_t stride = (size_t)n * H;
  float4 s = *(const float4*)&Part[i4 * 4];
  for (int c = 1; c < nch; ++c) {
    float4 p = *(const float4*)&Part[c * stride + i4 * 4];
    s.x += p.x; s.y += p.y; s.z += p.z; s.w += p.w;
  }
  float4 y = *(const float4*)&Y[i4 * 4];
  float d = RS ? rsqrtf(dv[row] + 2.0f) : dv[row];
  float4 v;
  v.x = d * (s.x + 2.0f * y.x) + bias[c4];
  v.y = d * (s.y + 2.0f * y.y) + bias[c4 + 1];
  v.z = d * (s.z + 2.0f * y.z) + bias[c4 + 2];
  v.w = d * (s.w + 2.0f * y.w) + bias[c4 + 3];
  if (relu) {
    v.x = fmaxf(v.x, 0.f); v.y = fmaxf(v.y, 0.f);
    v.z = fmaxf(v.z, 0.f); v.w = fmaxf(v.w, 0.f);
  }
  *(float4*)&Out[i4 * 4] = v;
  if (SCORE) {
    float sc = v.x * w[c4] + v.y * w[c4 + 1] + v.z * w[c4 + 2] + v.w * w[c4 + 3];
#pragma unroll
    for (int o = 16; o > 0; o >>= 1) sc += __shfl_down(sc, o, 32);
    if ((tid & 31) == 0) score[row] = tanhf(sc / wn);
  }
}

// ---- parallel rank-based top-k (replaces single-block bitonic) ----
// Keys distinct (idx in low bits) -> rank = #smaller keys = exact sorted position.
// perm[rank]=idx for rank<k ; inv[idx]=rank or -1. Identical result to a full sort.
__global__ __launch_bounds__(256) void k_topk_rank(const float* __restrict__ score,
                                                   int* __restrict__ perm,
                                                   int* __restrict__ inv, int n) {
  __shared__ unsigned long long keys[4096];
  int tid = threadIdx.x;
  for (int i = tid; i < n; i += 256) {
    unsigned u = __float_as_uint(score[i]);
    u = (u & 0x80000000u) ? ~u : (u | 0x80000000u);  // orderable ascending
    u = ~u;                                          // descending score
    keys[i] = (((unsigned long long)u) << 32) | (unsigned)i;
  }
  __syncthreads();
  int gid = blockIdx.x * 256 + tid;
  unsigned long long my = keys[gid];
  int rank = 0;
  for (int j = 0; j < n; j += 8) {
#pragma unroll
    for (int q = 0; q < 8; ++q) rank += (keys[j + q] < my) ? 1 : 0;
  }
  int kk = n >> 1;
  int idx = (int)(my & 0xffffffffu);
  if (rank < kk) perm[rank] = idx;
  inv[idx] = (rank < kk) ? rank : -1;
}

__global__ void k_segsum(const float* __restrict__ h, const int* __restrict__ batch,
                         float* __restrict__ g, int n) {
  int c = threadIdx.x;
  int r0 = blockIdx.x * 32;
  int rend = min(r0 + 32, n);
  float acc = 0.f;
  int cur = batch[r0];
  for (int r = r0; r < rend; ++r) {
    int b = batch[r];
    if (b != cur) { atomicAdd(&g[cur * H + c], acc); acc = 0.f; cur = b; }
    acc += h[(size_t)r * H + c];
  }
  atomicAdd(&g[cur * H + c], acc);
}

__global__ __launch_bounds__(256) void k_head(const float* __restrict__ g,
    const float* __restrict__ lins_w, const float* __restrict__ lins_b,
    const float* __restrict__ bn_g, const float* __restrict__ bn_b,
    const float* __restrict__ out_w, const float* __restrict__ out_b,
    float* __restrict__ out) {
  __shared__ float a[NG * H], b[NG * H];
  int tid = threadIdx.x;
  const float inv = 1.0f / sqrtf(1.0f + 1e-5f);
  for (int i = tid; i < NG * H; i += 256) a[i] = g[i];
  __syncthreads();
  for (int L = 0; L < 3; ++L) {
    for (int i = tid; i < NG * H; i += 256) {
      int c = i & 127;
      b[i] = a[i] * (bn_g[L * H + c] * inv) + bn_b[L * H + c];
    }
    __syncthreads();
    for (int i = tid; i < NG * H; i += 256) {
      int r = i >> 7, c = i & 127;
      float s = lins_b[L * H + c];
      for (int k2 = 0; k2 < H; ++k2) s += b[r * H + k2] * lins_w[(size_t)L * H * H + k2 * H + c];
      a[i] = tanhf(s);
    }
    __syncthreads();
  }
  for (int i = tid; i < NG * H; i += 256) {
    int c = i & 127;
    b[i] = a[i] * (bn_g[3 * H + c] * inv) + bn_b[3 * H + c];
  }
  __syncthreads();
  for (int i = tid; i < NG * 32; i += 256) {
    int r = i >> 5, o = i & 31;
    float s = out_b[o];
    for (int k2 = 0; k2 < H; ++k2) s += b[r * H + k2] * out_w[k2 * 32 + o];
    out[i] = s;
  }
}

extern "C" void kernel_launch(void* const* d_in, const int* in_sizes, int n_in,
                              void* d_out, int out_size, void* d_ws, size_t ws_size,
                              hipStream_t stream) {
  const float* x       = (const float*)d_in[0];
  const int*   ei      = (const int*)d_in[1];
  const int*   batch   = (const int*)d_in[2];
  const float* conv0_w = (const float*)d_in[3];
  const float* conv0_b = (const float*)d_in[4];
  const float* down_w  = (const float*)d_in[5];
  const float* down_b  = (const float*)d_in[6];
  const float* pool_w  = (const float*)d_in[7];
  const float* up_w    = (const float*)d_in[8];
  const float* up_b    = (const float*)d_in[9];
  const float* lins_w  = (const float*)d_in[10];
  const float* lins_b  = (const float*)d_in[11];
  const float* bn_g    = (const float*)d_in[12];
  const float* bn_b    = (const float*)d_in[13];
  const float* out_w   = (const float*)d_in[14];
  const float* out_b   = (const float*)d_in[15];
  int E = in_sizes[1] / 2;

  char* p = (char*)d_ws;
  auto alloc = [&](size_t bytes) {
    char* r = p;
    p += (bytes + 255) & ~(size_t)255;
    return r;
  };
  unsigned short* A1b  = (unsigned short*)alloc((size_t)2048 * 2048 * 2);
  unsigned short* YT   = (unsigned short*)alloc((size_t)128 * 4096 * 2);
  float*          A2m  = (float*)alloc((size_t)1024 * 1024 * 4);
  float*          A3   = (float*)alloc((size_t)512 * 512 * 4);
  float*          part = (float*)alloc((size_t)16 * 1024 * 1024 * 4);
  int* cnt    = (int*)alloc(4096 * 4);
  int* cursor = (int*)alloc(4096 * 4);   // contiguous with cnt -> single memset
  int* rowptr = (int*)alloc(4100 * 4);
  int* colidx = (int*)alloc((size_t)E * 4);
  int* inv0   = (int*)alloc(4096 * 4);
  int* inv1   = (int*)alloc(2048 * 4);
  int* inv2   = (int*)alloc(1024 * 4);
  float* dv0  = (float*)alloc(4096 * 4);
  float* dv1  = (float*)alloc(2048 * 4);
  float* dv2  = (float*)alloc(1024 * 4);   // raw rowsum
  float* dv3  = (float*)alloc(512 * 4);    // raw rowsum
  int* perm0  = (int*)alloc(2048 * 4);
  int* perm1  = (int*)alloc(1024 * 4);
  int* perm2  = (int*)alloc(512 * 4);
  float* score = (float*)alloc(4096 * 4);
  float* h0 = (float*)alloc((size_t)4096 * H * 4);
  float* h1 = (float*)alloc((size_t)2048 * H * 4);
  float* h2 = (float*)alloc((size_t)1024 * H * 4);
  float* h3 = (float*)alloc((size_t)512 * H * 4);
  float* t2 = (float*)alloc((size_t)4096 * H * 4);
  float* hu = (float*)alloc((size_t)4096 * H * 4);
  float* g  = (float*)alloc(NG * H * 4);

  // ---- CSR build (scan emits dv0) ----
  hipMemsetAsync(cnt, 0, 2 * 4096 * 4, stream);  // cnt + cursor
  k_hist<<<(E + 255) / 256, 256, 0, stream>>>(ei, E, cnt);
  k_scan<<<1, 1024, 0, stream>>>(cnt, rowptr, dv0, 4096);
  k_fill<<<(E + 255) / 256, 256, 0, stream>>>(ei, E, rowptr, cursor, colidx);

  // ---- conv0 (sparse) + fused score(pool_w) ----
  k_xw<0, 0, 0><<<4096 / 64, 256, 0, stream>>>(x, conv0_w, dv0, nullptr, nullptr, t2, nullptr, 4096, 64);
  k_spmm_fin<1><<<1024, 256, 0, stream>>>(rowptr, colidx, t2, dv0, conv0_b, h0, pool_w, score, 4096, 1);

  // ---- level 0 pooling (4096 -> 2048) ----
  k_topk_rank<<<4096 / 256, 256, 0, stream>>>(score, perm0, inv0, 4096);
  k_ata_rows<<<2048, 256, 0, stream>>>(rowptr, colidx, perm0, inv0, A1b, dv1, 2048);
  k_xw<1, 0, 1><<<2048 / 64, 256, 0, stream>>>(h0, down_w, dv1, perm0, score, t2, YT, 2048, 128);
  k_gcn_mfma<<<dim3(2048 / 64, 16), 256, 0, stream>>>(A1b, YT, part, 2048, 4096 / 16);
  k_gcn_fin<0, 1><<<2048 / 8, 256, 0, stream>>>(part, t2, dv1, down_b, h1, pool_w + H, score, 2048, 16, 1);

  // ---- level 1 pooling (2048 -> 1024) ----
  k_topk_rank<<<2048 / 256, 256, 0, stream>>>(score, perm1, inv1, 2048);
  k_ata_mfma_g<<<dim3(16, 16, 4), 256, 0, stream>>>(A1b, perm1, part, 2048, 1024, 512);
  k_ata_fin<4><<<1024, 256, 0, stream>>>(part, A2m, dv2, 1024);
  k_xw<1, 1, 0><<<1024 / 64, 256, 0, stream>>>(h1, down_w + (size_t)H * H, dv2, perm1, score, t2, nullptr, 1024, 128);
  k_gcn_part<<<dim3(1024 / 64, 8), 256, 0, stream>>>(A2m, t2, part, 1024, 128);
  k_gcn_fin<1, 1><<<1024 / 8, 256, 0, stream>>>(part, t2, dv2, down_b + H, h2, pool_w + 2 * H, score, 1024, 8, 1);

  // ---- level 2 pooling (1024 -> 512) ----
  k_topk_rank<<<1024 / 256, 256, 0, stream>>>(score, perm2, inv2, 1024);
  k_ata_sk_part<<<dim3(8, 8, 8), 256, 0, stream>>>(A2m, perm2, part, 1024, 512, 128);
  k_ata_fin<8><<<512, 128, 0, stream>>>(part, A3, dv3, 512);
  k_xw<1, 1, 0><<<512 / 64, 256, 0, stream>>>(h2, down_w + (size_t)2 * H * H, dv3, perm2, score, t2, nullptr, 512, 128);
  k_gcn_part<<<dim3(512 / 64, 8), 256, 0, stream>>>(A3, t2, part, 512, 64);
  k_gcn_fin<1, 0><<<512 / 8, 256, 0, stream>>>(part, t2, dv3, down_b + 2 * H, h3, nullptr, nullptr, 512, 8, 1);

  // ---- up path ----
  k_xw<2, 1, 0><<<1024 / 64, 256, 0, stream>>>(h2, up_w, dv2, inv2, h3, t2, nullptr, 1024, 128);
  k_gcn_part<<<dim3(1024 / 64, 8), 256, 0, stream>>>(A2m, t2, part, 1024, 128);
  k_gcn_fin<1, 0><<<1024 / 8, 256, 0, stream>>>(part, t2, dv2, up_b, hu, nullptr, nullptr, 1024, 8, 1);

  k_xw<2, 0, 1><<<2048 / 64, 256, 0, stream>>>(h1, up_w + (size_t)H * H, dv1, inv1, hu, t2, YT, 2048, 128);
  k_gcn_mfma<<<dim3(2048 / 64, 16), 256, 0, stream>>>(A1b, YT, part, 2048, 4096 / 16);
  k_gcn_fin<0, 0><<<2048 / 8, 256, 0, stream>>>(part, t2, dv1, up_b + H, hu, nullptr, nullptr, 2048, 16, 1);

  k_xw<2, 0, 0><<<4096 / 64, 256, 0, stream>>>(h0, up_w + (size_t)2 * H * H, dv0, inv0, hu, t2, nullptr, 4096, 128);
  k_spmm_fin<0><<<1024, 256, 0, stream>>>(rowptr, colidx, t2, dv0, up_b + 2 * H, hu, nullptr, nullptr, 4096, 0);

  // ---- pool + head ----
  hipMemsetAsync(g, 0, NG * H * 4, stream);
  k_segsum<<<4096 / 32, 128, 0, stream>>>(hu, batch, g, 4096);
  k_head<<<1, 256, 0, stream>>>(g, lins_w, lins_b, bn_g, bn_b, out_w, out_b, (float*)d_out);
}

// Round 14
// 502.131 us; speedup vs baseline: 1.0470x; 1.0470x over previous
//
#include <hip/hip_runtime.h>
#include <math.h>

#define H 128
#define NG 8

typedef __attribute__((ext_vector_type(8))) short bf16x8;
typedef __attribute__((ext_vector_type(8))) unsigned short ushort8;
typedef __attribute__((ext_vector_type(4))) float f32x4;

static __device__ __forceinline__ float b2f(unsigned short u) {
  union { unsigned int i; float f; } v;
  v.i = ((unsigned int)u) << 16;
  return v.f;
}
static __device__ __forceinline__ unsigned short f2b(float f) {
  return (unsigned short)(__float_as_uint(f) >> 16);  // truncation; exact for small ints
}
// orderable key: descending score, ascending index ties (matches jax.lax.top_k)
static __device__ __forceinline__ unsigned long long keyof(float sc, int i) {
  unsigned u = __float_as_uint(sc);
  u = (u & 0x80000000u) ? ~u : (u | 0x80000000u);
  u = ~u;
  return (((unsigned long long)u) << 32) | (unsigned)i;
}

// ---------------- CSR build ----------------
__global__ void k_hist(const int* __restrict__ ei, int E, int* __restrict__ cnt) {
  int e = blockIdx.x * 256 + threadIdx.x;
  if (e >= E) return;
  atomicAdd(&cnt[ei[E + e]], 1);
}

// scan + dv0 = rsqrt(cnt+2) fused
__global__ __launch_bounds__(1024) void k_scan(const int* __restrict__ cnt,
                                               int* __restrict__ rowptr,
                                               float* __restrict__ dv, int n) {
  __shared__ int sums[1024];
  int tid = threadIdx.x;
  int base = tid * 4;
  int v0 = 0, v1 = 0, v2 = 0, v3 = 0;
  if (base < n) { v0 = cnt[base]; v1 = cnt[base + 1]; v2 = cnt[base + 2]; v3 = cnt[base + 3]; }
  int s = v0 + v1 + v2 + v3;
  sums[tid] = s;
  __syncthreads();
  for (int off = 1; off < 1024; off <<= 1) {
    int t = (tid >= off) ? sums[tid - off] : 0;
    __syncthreads();
    sums[tid] += t;
    __syncthreads();
  }
  int excl = sums[tid] - s;
  if (base < n) {
    rowptr[base] = excl;
    rowptr[base + 1] = excl + v0;
    rowptr[base + 2] = excl + v0 + v1;
    rowptr[base + 3] = excl + v0 + v1 + v2;
    dv[base] = rsqrtf((float)v0 + 2.0f);
    dv[base + 1] = rsqrtf((float)v1 + 2.0f);
    dv[base + 2] = rsqrtf((float)v2 + 2.0f);
    dv[base + 3] = rsqrtf((float)v3 + 2.0f);
  }
  if (tid == 1023) rowptr[n] = sums[1023];
}

__global__ void k_fill(const int* __restrict__ ei, int E, const int* __restrict__ rowptr,
                       int* __restrict__ cursor, int* __restrict__ colidx) {
  int e = blockIdx.x * 256 + threadIdx.x;
  if (e >= E) return;
  int r = ei[E + e], c = ei[e];
  int p = atomicAdd(&cursor[r], 1);
  colidx[rowptr[r] + p] = c;
}

// Y[r,c] = d(r) * sum_k X'[r,k] W[k,c]; RS: dv holds rowsum; EMIT: also write YT bf16 hi/lo limbs
// MODE 0: X'=X ; 1 (pool): X[perm[r]]*score ; 2 (skip): X[r]+prev[inv[r]]
template <int MODE, int RS, int EMIT>
__global__ __launch_bounds__(256) void k_xw(const float* __restrict__ X,
                                            const float* __restrict__ W,
                                            const float* __restrict__ dv,
                                            const int* __restrict__ idx,
                                            const float* __restrict__ aux,
                                            float* __restrict__ Y,
                                            unsigned short* __restrict__ YT,
                                            int n, int F) {
  __shared__ float Xs[64][36];
  __shared__ float Ws[32][132];
  __shared__ int ridx[64];
  __shared__ float rscl[64];
  int tid = threadIdx.x;
  int rowBase = blockIdx.x * 64;
  if (MODE == 1) {
    if (tid < 64) {
      int pp = idx[rowBase + tid];
      ridx[tid] = pp;
      rscl[tid] = aux[pp];
    }
  } else if (MODE == 2) {
    if (tid < 64) ridx[tid] = idx[rowBase + tid];
  }
  if (MODE != 0) __syncthreads();
  int r0 = (tid >> 5) << 3;
  int c0 = (tid & 31) << 2;
  float acc[8][4] = {};
  for (int k0 = 0; k0 < F; k0 += 32) {
#pragma unroll
    for (int it = 0, e = tid; it < 8; ++it, e += 256) {
      int ii = e >> 5, kk = e & 31;
      int gk = k0 + kk;
      float v;
      if (MODE == 0) {
        v = X[(size_t)(rowBase + ii) * F + gk];
      } else if (MODE == 1) {
        v = X[(size_t)ridx[ii] * F + gk] * rscl[ii];
      } else {
        v = X[(size_t)(rowBase + ii) * F + gk];
        int iv = ridx[ii];
        if (iv >= 0) v += aux[(size_t)iv * H + gk];
      }
      Xs[ii][kk] = v;
    }
#pragma unroll
    for (int it = 0, e = tid; it < 4; ++it, e += 256) {
      int kk = e >> 5, cc4 = e & 31;
      *(float4*)&Ws[kk][cc4 << 2] = *(const float4*)&W[(size_t)(k0 + kk) * H + (cc4 << 2)];
    }
    __syncthreads();
#pragma unroll
    for (int kk = 0; kk < 32; kk += 4) {
      float4 a4[8], w4[4];
#pragma unroll
      for (int i = 0; i < 8; ++i) a4[i] = *(const float4*)&Xs[r0 + i][kk];
#pragma unroll
      for (int s = 0; s < 4; ++s) w4[s] = *(const float4*)&Ws[kk + s][c0];
#pragma unroll
      for (int i = 0; i < 8; ++i) {
        float av[4] = {a4[i].x, a4[i].y, a4[i].z, a4[i].w};
#pragma unroll
        for (int s = 0; s < 4; ++s) {
          float wv[4] = {w4[s].x, w4[s].y, w4[s].z, w4[s].w};
#pragma unroll
          for (int j = 0; j < 4; ++j) acc[i][j] = fmaf(av[s], wv[j], acc[i][j]);
        }
      }
    }
    __syncthreads();
  }
  float vout[8][4];
#pragma unroll
  for (int i = 0; i < 8; ++i) {
    int row = rowBase + r0 + i;
    float d = RS ? rsqrtf(dv[row] + 2.0f) : dv[row];
#pragma unroll
    for (int j = 0; j < 4; ++j) vout[i][j] = d * acc[i][j];
    *(float4*)&Y[(size_t)row * H + c0] =
        make_float4(vout[i][0], vout[i][1], vout[i][2], vout[i][3]);
  }
  if (EMIT) {
#pragma unroll
    for (int j = 0; j < 4; ++j) {
      ushort8 hi, lo;
#pragma unroll
      for (int i = 0; i < 8; ++i) {
        float v = vout[i][j];
        unsigned short hh = f2b(v);
        hi[i] = hh;
        lo[i] = f2b(v - b2f(hh));
      }
      int c = c0 + j;
      *(ushort8*)&YT[(size_t)c * (2 * n) + rowBase + r0] = hi;
      *(ushort8*)&YT[(size_t)c * (2 * n) + n + rowBase + r0] = lo;
    }
  }
}

// sparse GCN epilogue; lane covers cols 2*lane, 2*lane+1. SCORE: emit tanh((out@w)/||w||)
template <int SCORE>
__global__ void k_spmm_fin(const int* __restrict__ rowptr, const int* __restrict__ colidx,
                           const float* __restrict__ Y, const float* __restrict__ dv,
                           const float* __restrict__ bias, float* __restrict__ Out,
                           const float* __restrict__ w, float* __restrict__ score,
                           int n, int relu) {
  __shared__ float wn;
  int tid = threadIdx.x;
  if (SCORE) {
    if (tid < 64) {
      float s = w[tid] * w[tid] + w[tid + 64] * w[tid + 64];
#pragma unroll
      for (int o = 32; o > 0; o >>= 1) s += __shfl_down(s, o);
      if (tid == 0) wn = sqrtf(s);
    }
    __syncthreads();
  }
  int row = blockIdx.x * 4 + (tid >> 6);
  int lane = tid & 63;
  if (row >= n) return;
  int s = rowptr[row], e = rowptr[row + 1];
  int c2 = lane * 2;
  float a0 = 0.f, a1 = 0.f;
  int i = s;
  for (; i + 1 < e; i += 2) {
    int cA = colidx[i], cB = colidx[i + 1];
    float2 yA = *(const float2*)&Y[(size_t)cA * H + c2];
    float2 yB = *(const float2*)&Y[(size_t)cB * H + c2];
    a0 += yA.x + yB.x;
    a1 += yA.y + yB.y;
  }
  if (i < e) {
    int c = colidx[i];
    float2 y = *(const float2*)&Y[(size_t)c * H + c2];
    a0 += y.x;
    a1 += y.y;
  }
  float d = dv[row];
  float2 yr = *(const float2*)&Y[(size_t)row * H + c2];
  float v0 = d * (a0 + 2.0f * yr.x) + bias[c2];
  float v1 = d * (a1 + 2.0f * yr.y) + bias[c2 + 1];
  if (relu) { v0 = fmaxf(v0, 0.f); v1 = fmaxf(v1, 0.f); }
  *(float2*)&Out[(size_t)row * H + c2] = make_float2(v0, v1);
  if (SCORE) {
    float sc = v0 * w[c2] + v1 * w[c2 + 1];
#pragma unroll
    for (int o = 32; o > 0; o >>= 1) sc += __shfl_down(sc, o);
    if (lane == 0) score[row] = tanhf(sc / wn);
  }
}

// level-0 ATA, row-wise (LDS int accumulators) -> bf16 row + dv fused
__global__ __launch_bounds__(256) void k_ata_rows(const int* __restrict__ rowptr,
                                                  const int* __restrict__ colidx,
                                                  const int* __restrict__ perm,
                                                  const int* __restrict__ inv,
                                                  unsigned short* __restrict__ Ab,
                                                  float* __restrict__ dv, int kdim) {
  __shared__ int acc[2048];
  __shared__ int wsum[4];
  int i = blockIdx.x;
  int tid = threadIdx.x;
  for (int j = tid; j < kdim; j += 256) acc[j] = 0;
  __syncthreads();
  int p = perm[i];
  int s = rowptr[p], e = rowptr[p + 1];
  int deg = e - s;
  int wave = tid >> 6, lane = tid & 63;
  for (int q = wave; q <= deg; q += 4) {
    int kn = (q < deg) ? colidx[s + q] : p;
    int s2 = rowptr[kn], e2 = rowptr[kn + 1];
    for (int idx = s2 + lane; idx <= e2; idx += 64) {
      int j = (idx < e2) ? colidx[idx] : kn;
      int ii = inv[j];
      if (ii >= 0) atomicAdd(&acc[ii], 1);
    }
  }
  __syncthreads();
  int rs = 0;
  {
    int j0 = tid * 8;
    ushort8 v;
#pragma unroll
    for (int q = 0; q < 8; ++q) {
      int j = j0 + q;
      int c = (j == i) ? 0 : acc[j];
      rs += c;
      v[q] = f2b((float)c);
    }
    *(ushort8*)&Ab[(size_t)i * kdim + j0] = v;
  }
#pragma unroll
  for (int o = 32; o > 0; o >>= 1) rs += __shfl_down(rs, o);
  if (lane == 0) wsum[wave] = rs;
  __syncthreads();
  if (tid == 0) dv[i] = rsqrtf((float)(wsum[0] + wsum[1] + wsum[2] + wsum[3]) + 2.0f);
}

// level-1 ATA partial: bf16 MFMA (gather + +I fused), z-chunk private partial
__global__ __launch_bounds__(256) void k_ata_mfma_g(const unsigned short* __restrict__ Ab,
                                                    const int* __restrict__ perm,
                                                    float* __restrict__ PartC,
                                                    int n, int k, int KC) {
  __shared__ __align__(16) unsigned short As[64][64];
  __shared__ __align__(16) unsigned short Bs[64][64];
  __shared__ int pr[64], pc[64];
  int tid = threadIdx.x;
  int w = tid >> 6, ln = tid & 63;
  int l15 = ln & 15, l4 = ln >> 4;
  int br = blockIdx.y, bc = blockIdx.x;
  if (tid < 64) pr[tid] = perm[br * 64 + tid];
  else if (tid < 128) pc[tid - 64] = perm[bc * 64 + (tid - 64)];
  __syncthreads();
  f32x4 acc[4] = {};
  int k0s = blockIdx.z * KC;
  for (int k0 = k0s; k0 < k0s + KC; k0 += 64) {
#pragma unroll
    for (int it = 0; it < 2; ++it) {
      int e = tid + it * 256;
      int row = e >> 3, ch = e & 7;
      int sch = (ch ^ (row & 7)) * 8;
      int base = k0 + ch * 8;
      {
        int p = pr[row];
        ushort8 v = *(const ushort8*)&Ab[(size_t)p * n + base];
#pragma unroll
        for (int q = 0; q < 8; ++q)
          if (base + q == p) v[q] = f2b(b2f(v[q]) + 1.0f);
        *(ushort8*)&As[row][sch] = v;
      }
      {
        int p = pc[row];
        ushort8 v = *(const ushort8*)&Ab[(size_t)p * n + base];
#pragma unroll
        for (int q = 0; q < 8; ++q)
          if (base + q == p) v[q] = f2b(b2f(v[q]) + 1.0f);
        *(ushort8*)&Bs[row][sch] = v;
      }
    }
    __syncthreads();
#pragma unroll
    for (int s = 0; s < 2; ++s) {
      int arow = w * 16 + l15;
      bf16x8 af = *(const bf16x8*)&As[arow][((s * 4 + l4) ^ (arow & 7)) * 8];
#pragma unroll
      for (int f = 0; f < 4; ++f) {
        int brow = f * 16 + l15;
        bf16x8 bfr = *(const bf16x8*)&Bs[brow][((s * 4 + l4) ^ (brow & 7)) * 8];
        acc[f] = __builtin_amdgcn_mfma_f32_16x16x32_bf16(af, bfr, acc[f], 0, 0, 0);
      }
    }
    __syncthreads();
  }
  float* out = PartC + (size_t)blockIdx.z * k * k;
#pragma unroll
  for (int f = 0; f < 4; ++f) {
#pragma unroll
    for (int r = 0; r < 4; ++r) {
      int gi = br * 64 + w * 16 + l4 * 4 + r;
      int gj = bc * 64 + f * 16 + l15;
      out[(size_t)gi * k + gj] = acc[f][r];
    }
  }
}

// level-2 ATA partial: fp32, gather + +I, z-chunk private partial (no atomics)
__global__ __launch_bounds__(256) void k_ata_sk_part(const float* __restrict__ A,
                                                     const int* __restrict__ perm,
                                                     float* __restrict__ PartC,
                                                     int n, int k, int CK) {
  int bc = blockIdx.x, br = blockIdx.y;
  __shared__ float As[64][36];
  __shared__ float Bs[64][36];
  __shared__ int pr[64], pc[64];
  int tid = threadIdx.x;
  if (tid < 64) pr[tid] = perm[br * 64 + tid];
  else if (tid < 128) pc[tid - 64] = perm[bc * 64 + (tid - 64)];
  __syncthreads();
  int ty = tid >> 4;
  int tx = tid & 15;
  float acc[4][4] = {};
  int k0s = blockIdx.z * CK;
  for (int k0 = k0s; k0 < k0s + CK; k0 += 32) {
#pragma unroll
    for (int it = 0, e = tid; it < 8; ++it, e += 256) {
      int ii = e >> 5, kk = e & 31;
      int gk = k0 + kk;
      int p = pr[ii];
      As[ii][kk] = A[(size_t)p * n + gk] + ((p == gk) ? 1.0f : 0.0f);
      p = pc[ii];
      Bs[ii][kk] = A[(size_t)p * n + gk] + ((p == gk) ? 1.0f : 0.0f);
    }
    __syncthreads();
#pragma unroll
    for (int kk = 0; kk < 32; kk += 4) {
      float4 a4[4], b4[4];
#pragma unroll
      for (int i = 0; i < 4; ++i) a4[i] = *(const float4*)&As[ty + 16 * i][kk];
#pragma unroll
      for (int j = 0; j < 4; ++j) b4[j] = *(const float4*)&Bs[tx + 16 * j][kk];
#pragma unroll
      for (int i = 0; i < 4; ++i) {
        float av[4] = {a4[i].x, a4[i].y, a4[i].z, a4[i].w};
#pragma unroll
        for (int j = 0; j < 4; ++j) {
          float bv[4] = {b4[j].x, b4[j].y, b4[j].z, b4[j].w};
#pragma unroll
          for (int s = 0; s < 4; ++s) acc[i][j] = fmaf(av[s], bv[s], acc[i][j]);
        }
      }
    }
    __syncthreads();
  }
  float* out = PartC + (size_t)blockIdx.z * k * k;
#pragma unroll
  for (int i = 0; i < 4; ++i) {
    int gi = br * 64 + ty + 16 * i;
#pragma unroll
    for (int j = 0; j < 4; ++j) {
      int gj = bc * 64 + tx + 16 * j;
      out[(size_t)gi * k + gj] = acc[i][j];
    }
  }
}

// sum NCH ATA partials, zero diag, write C, emit raw rowsum. blockDim = k/4.
template <int NCH>
__global__ void k_ata_fin(const float* __restrict__ PartC, float* __restrict__ C,
                          float* __restrict__ rowsum, int k) {
  __shared__ float wsum[4];
  int gi = blockIdx.x;
  int tid = threadIdx.x;
  int j4 = tid * 4;
  size_t stride = (size_t)k * k;
  size_t off = (size_t)gi * k + j4;
  float4 s = *(const float4*)&PartC[off];
#pragma unroll
  for (int z = 1; z < NCH; ++z) {
    float4 p = *(const float4*)&PartC[z * stride + off];
    s.x += p.x; s.y += p.y; s.z += p.z; s.w += p.w;
  }
  if (gi >= j4 && gi < j4 + 4) ((float*)&s)[gi - j4] = 0.0f;
  *(float4*)&C[off] = s;
  float part = s.x + s.y + s.z + s.w;
  int lane = tid & 63, wave = tid >> 6;
#pragma unroll
  for (int o = 32; o > 0; o >>= 1) part += __shfl_down(part, o);
  if (lane == 0) wsum[wave] = part;
  __syncthreads();
  if (tid == 0) {
    int nw = blockDim.x >> 6;
    float t = 0.f;
    for (int q = 0; q < nw; ++q) t += wsum[q];
    rowsum[gi] = t;
  }
}

// Partial A@Y via bf16 MFMA over virtual K=2n (hi|lo limbs). Split-K private partials.
__global__ __launch_bounds__(256) void k_gcn_mfma(const unsigned short* __restrict__ A,
                                                  const unsigned short* __restrict__ YT,
                                                  float* __restrict__ Part, int n, int VK) {
  __shared__ __align__(16) unsigned short As[64][64];
  __shared__ __align__(16) unsigned short Bs[128][64];
  int tid = threadIdx.x;
  int w = tid >> 6, ln = tid & 63;
  int l15 = ln & 15, l4 = ln >> 4;
  int rowBase = blockIdx.x * 64;
  float* out = Part + (size_t)blockIdx.y * n * H;
  f32x4 acc[8] = {};
  int vk0s = blockIdx.y * VK;
  for (int vk0 = vk0s; vk0 < vk0s + VK; vk0 += 64) {
    int ka = vk0 & (n - 1);
#pragma unroll
    for (int it = 0; it < 2; ++it) {
      int e = tid + it * 256;
      int row = e >> 3, ch = e & 7;
      int sch = (ch ^ (row & 7)) * 8;
      *(ushort8*)&As[row][sch] = *(const ushort8*)&A[(size_t)(rowBase + row) * n + ka + ch * 8];
    }
#pragma unroll
    for (int it = 0; it < 4; ++it) {
      int e = tid + it * 256;
      int row = e >> 3, ch = e & 7;
      int sch = (ch ^ (row & 7)) * 8;
      *(ushort8*)&Bs[row][sch] = *(const ushort8*)&YT[(size_t)row * (2 * n) + vk0 + ch * 8];
    }
    __syncthreads();
#pragma unroll
    for (int s = 0; s < 2; ++s) {
      int arow = w * 16 + l15;
      bf16x8 af = *(const bf16x8*)&As[arow][((s * 4 + l4) ^ (arow & 7)) * 8];
#pragma unroll
      for (int f = 0; f < 8; ++f) {
        int brow = f * 16 + l15;
        bf16x8 bfr = *(const bf16x8*)&Bs[brow][((s * 4 + l4) ^ (brow & 7)) * 8];
        acc[f] = __builtin_amdgcn_mfma_f32_16x16x32_bf16(af, bfr, acc[f], 0, 0, 0);
      }
    }
    __syncthreads();
  }
#pragma unroll
  for (int f = 0; f < 8; ++f) {
#pragma unroll
    for (int r = 0; r < 4; ++r) {
      int row = rowBase + w * 16 + l4 * 4 + r;
      out[(size_t)row * H + f * 16 + l15] = acc[f][r];
    }
  }
}

// fp32 dense GCN partial (split-K, private partials)
__global__ __launch_bounds__(256) void k_gcn_part(const float* __restrict__ A,
                                                  const float* __restrict__ Y,
                                                  float* __restrict__ Part,
                                                  int n, int KC) {
  __shared__ float As[64][36];
  __shared__ float Ys[32][132];
  int tid = threadIdx.x;
  int r0 = (tid >> 5) << 3;
  int c0 = (tid & 31) << 2;
  size_t rowBase = (size_t)blockIdx.x * 64;
  int k0s = blockIdx.y * KC;
  float* out = Part + (size_t)blockIdx.y * n * H;
  float acc[8][4] = {};
  for (int k0 = k0s; k0 < k0s + KC; k0 += 32) {
#pragma unroll
    for (int it = 0, e = tid; it < 8; ++it, e += 256) {
      int ii = e >> 5, kk = e & 31;
      As[ii][kk] = A[(rowBase + ii) * (size_t)n + k0 + kk];
    }
#pragma unroll
    for (int it = 0, e = tid; it < 4; ++it, e += 256) {
      int kk = e >> 5, cc4 = e & 31;
      *(float4*)&Ys[kk][cc4 << 2] = *(const float4*)&Y[(size_t)(k0 + kk) * H + (cc4 << 2)];
    }
    __syncthreads();
#pragma unroll
    for (int kk = 0; kk < 32; kk += 4) {
      float4 a4[8], y4[4];
#pragma unroll
      for (int i = 0; i < 8; ++i) a4[i] = *(const float4*)&As[r0 + i][kk];
#pragma unroll
      for (int s = 0; s < 4; ++s) y4[s] = *(const float4*)&Ys[kk + s][c0];
#pragma unroll
      for (int i = 0; i < 8; ++i) {
        float av[4] = {a4[i].x, a4[i].y, a4[i].z, a4[i].w};
#pragma unroll
        for (int s = 0; s < 4; ++s) {
          float yv[4] = {y4[s].x, y4[s].y, y4[s].z, y4[s].w};
#pragma unroll
          for (int j = 0; j < 4; ++j) acc[i][j] = fmaf(av[s], yv[j], acc[i][j]);
        }
      }
    }
    __syncthreads();
  }
#pragma unroll
  for (int i = 0; i < 8; ++i) {
    size_t row = rowBase + r0 + i;
    *(float4*)&out[row * H + c0] = make_float4(acc[i][0], acc[i][1], acc[i][2], acc[i][3]);
  }
}

// Out = act(d .* (sum Part + 2Y) + bias); RS: dv holds rowsum; SCORE: emit score
template <int RS, int SCORE>
__global__ void k_gcn_fin(const float* __restrict__ Part, const float* __restrict__ Y,
                          const float* __restrict__ dv, const float* __restrict__ bias,
                          float* __restrict__ Out,
                          const float* __restrict__ w, float* __restrict__ score,
                          int n, int nch, int relu) {
  __shared__ float wn;
  int tid = threadIdx.x;
  if (SCORE) {
    if (tid < 64) {
      float s = w[tid] * w[tid] + w[tid + 64] * w[tid + 64];
#pragma unroll
      for (int o = 32; o > 0; o >>= 1) s += __shfl_down(s, o);
      if (tid == 0) wn = sqrtf(s);
    }
    __syncthreads();
  }
  int i4 = blockIdx.x * 256 + tid;
  int row = i4 >> 5, c4 = (i4 & 31) * 4;
  size_t stride = (size_t)n * H;
  float4 s = *(const float4*)&Part[i4 * 4];
  for (int c = 1; c < nch; ++c) {
    float4 p = *(const float4*)&Part[c * stride + i4 * 4];
    s.x += p.x; s.y += p.y; s.z += p.z; s.w += p.w;
  }
  float4 y = *(const float4*)&Y[i4 * 4];
  float d = RS ? rsqrtf(dv[row] + 2.0f) : dv[row];
  float4 v;
  v.x = d * (s.x + 2.0f * y.x) + bias[c4];
  v.y = d * (s.y + 2.0f * y.y) + bias[c4 + 1];
  v.z = d * (s.z + 2.0f * y.z) + bias[c4 + 2];
  v.w = d * (s.w + 2.0f * y.w) + bias[c4 + 3];
  if (relu) {
    v.x = fmaxf(v.x, 0.f); v.y = fmaxf(v.y, 0.f);
    v.z = fmaxf(v.z, 0.f); v.w = fmaxf(v.w, 0.f);
  }
  *(float4*)&Out[i4 * 4] = v;
  if (SCORE) {
    float sc = v.x * w[c4] + v.y * w[c4 + 1] + v.z * w[c4 + 2] + v.w * w[c4 + 3];
#pragma unroll
    for (int o = 16; o > 0; o >>= 1) sc += __shfl_down(sc, o, 32);
    if ((tid & 31) == 0) score[row] = tanhf(sc / wn);
  }
}

// ---- 2D-parallel rank top-k: count smaller keys per 512-key j-chunk ----
// rank pre-zeroed. Keys distinct -> ranks are a permutation of 0..n-1.
__global__ __launch_bounds__(256) void k_rank_count(const float* __restrict__ score,
                                                    int* __restrict__ rank, int n) {
  __shared__ unsigned long long jk[512];
  int tid = threadIdx.x;
  int jbase = blockIdx.y * 512;
  jk[tid] = keyof(score[jbase + tid], jbase + tid);
  jk[tid + 256] = keyof(score[jbase + tid + 256], jbase + tid + 256);
  __syncthreads();
  int gid = blockIdx.x * 256 + tid;
  unsigned long long my = keyof(score[gid], gid);
  int c = 0;
#pragma unroll 8
  for (int j = 0; j < 512; ++j) c += (jk[j] < my) ? 1 : 0;
  atomicAdd(&rank[gid], c);
}

// scatter: perm[rank]=i (rank<k), inv[i]=rank or -1
__global__ void k_rank_scatter(const int* __restrict__ rank, int* __restrict__ perm,
                               int* __restrict__ inv, int n) {
  int i = blockIdx.x * 256 + threadIdx.x;
  if (i >= n) return;
  int r = rank[i];
  int kk = n >> 1;
  if (r < kk) perm[r] = i;
  inv[i] = (r < kk) ? r : -1;
}

__global__ void k_segsum(const float* __restrict__ h, const int* __restrict__ batch,
                         float* __restrict__ g, int n) {
  int c = threadIdx.x;
  int r0 = blockIdx.x * 32;
  int rend = min(r0 + 32, n);
  float acc = 0.f;
  int cur = batch[r0];
  for (int r = r0; r < rend; ++r) {
    int b = batch[r];
    if (b != cur) { atomicAdd(&g[cur * H + c], acc); acc = 0.f; cur = b; }
    acc += h[(size_t)r * H + c];
  }
  atomicAdd(&g[cur * H + c], acc);
}

__global__ __launch_bounds__(256) void k_head(const float* __restrict__ g,
    const float* __restrict__ lins_w, const float* __restrict__ lins_b,
    const float* __restrict__ bn_g, const float* __restrict__ bn_b,
    const float* __restrict__ out_w, const float* __restrict__ out_b,
    float* __restrict__ out) {
  __shared__ float a[NG * H], b[NG * H];
  int tid = threadIdx.x;
  const float inv = 1.0f / sqrtf(1.0f + 1e-5f);
  for (int i = tid; i < NG * H; i += 256) a[i] = g[i];
  __syncthreads();
  for (int L = 0; L < 3; ++L) {
    for (int i = tid; i < NG * H; i += 256) {
      int c = i & 127;
      b[i] = a[i] * (bn_g[L * H + c] * inv) + bn_b[L * H + c];
    }
    __syncthreads();
    for (int i = tid; i < NG * H; i += 256) {
      int r = i >> 7, c = i & 127;
      float s = lins_b[L * H + c];
      for (int k2 = 0; k2 < H; ++k2) s += b[r * H + k2] * lins_w[(size_t)L * H * H + k2 * H + c];
      a[i] = tanhf(s);
    }
    __syncthreads();
  }
  for (int i = tid; i < NG * H; i += 256) {
    int c = i & 127;
    b[i] = a[i] * (bn_g[3 * H + c] * inv) + bn_b[3 * H + c];
  }
  __syncthreads();
  for (int i = tid; i < NG * 32; i += 256) {
    int r = i >> 5, o = i & 31;
    float s = out_b[o];
    for (int k2 = 0; k2 < H; ++k2) s += b[r * H + k2] * out_w[k2 * 32 + o];
    out[i] = s;
  }
}

extern "C" void kernel_launch(void* const* d_in, const int* in_sizes, int n_in,
                              void* d_out, int out_size, void* d_ws, size_t ws_size,
                              hipStream_t stream) {
  const float* x       = (const float*)d_in[0];
  const int*   ei      = (const int*)d_in[1];
  const int*   batch   = (const int*)d_in[2];
  const float* conv0_w = (const float*)d_in[3];
  const float* conv0_b = (const float*)d_in[4];
  const float* down_w  = (const float*)d_in[5];
  const float* down_b  = (const float*)d_in[6];
  const float* pool_w  = (const float*)d_in[7];
  const float* up_w    = (const float*)d_in[8];
  const float* up_b    = (const float*)d_in[9];
  const float* lins_w  = (const float*)d_in[10];
  const float* lins_b  = (const float*)d_in[11];
  const float* bn_g    = (const float*)d_in[12];
  const float* bn_b    = (const float*)d_in[13];
  const float* out_w   = (const float*)d_in[14];
  const float* out_b   = (const float*)d_in[15];
  int E = in_sizes[1] / 2;

  char* p = (char*)d_ws;
  auto alloc = [&](size_t bytes) {
    char* r = p;
    p += (bytes + 255) & ~(size_t)255;
    return r;
  };
  unsigned short* A1b  = (unsigned short*)alloc((size_t)2048 * 2048 * 2);
  unsigned short* YT   = (unsigned short*)alloc((size_t)128 * 4096 * 2);
  float*          A2m  = (float*)alloc((size_t)1024 * 1024 * 4);
  float*          A3   = (float*)alloc((size_t)512 * 512 * 4);
  float*          part = (float*)alloc((size_t)16 * 1024 * 1024 * 4);
  // cnt, cursor, rank0, rank1, rank2 contiguous -> single memset
  int* cnt    = (int*)alloc(4096 * 4);
  int* cursor = (int*)alloc(4096 * 4);
  int* rank0  = (int*)alloc(4096 * 4);
  int* rank1  = (int*)alloc(2048 * 4);
  int* rank2  = (int*)alloc(1024 * 4);
  int* rowptr = (int*)alloc(4100 * 4);
  int* colidx = (int*)alloc((size_t)E * 4);
  int* inv0   = (int*)alloc(4096 * 4);
  int* inv1   = (int*)alloc(2048 * 4);
  int* inv2   = (int*)alloc(1024 * 4);
  float* dv0  = (float*)alloc(4096 * 4);
  float* dv1  = (float*)alloc(2048 * 4);
  float* dv2  = (float*)alloc(1024 * 4);   // raw rowsum
  float* dv3  = (float*)alloc(512 * 4);    // raw rowsum
  int* perm0  = (int*)alloc(2048 * 4);
  int* perm1  = (int*)alloc(1024 * 4);
  int* perm2  = (int*)alloc(512 * 4);
  float* score = (float*)alloc(4096 * 4);
  float* h0 = (float*)alloc((size_t)4096 * H * 4);
  float* h1 = (float*)alloc((size_t)2048 * H * 4);
  float* h2 = (float*)alloc((size_t)1024 * H * 4);
  float* h3 = (float*)alloc((size_t)512 * H * 4);
  float* t2 = (float*)alloc((size_t)4096 * H * 4);
  float* hu = (float*)alloc((size_t)4096 * H * 4);
  float* g  = (float*)alloc(NG * H * 4);

  // ---- CSR build (scan emits dv0); memset covers cnt+cursor+rank0+rank1+rank2 ----
  hipMemsetAsync(cnt, 0, (4096 + 4096 + 4096 + 2048 + 1024) * 4, stream);
  k_hist<<<(E + 255) / 256, 256, 0, stream>>>(ei, E, cnt);
  k_scan<<<1, 1024, 0, stream>>>(cnt, rowptr, dv0, 4096);
  k_fill<<<(E + 255) / 256, 256, 0, stream>>>(ei, E, rowptr, cursor, colidx);

  // ---- conv0 (sparse) + fused score(pool_w) ----
  k_xw<0, 0, 0><<<4096 / 64, 256, 0, stream>>>(x, conv0_w, dv0, nullptr, nullptr, t2, nullptr, 4096, 64);
  k_spmm_fin<1><<<1024, 256, 0, stream>>>(rowptr, colidx, t2, dv0, conv0_b, h0, pool_w, score, 4096, 1);

  // ---- level 0 pooling (4096 -> 2048) ----
  k_rank_count<<<dim3(4096 / 256, 4096 / 512), 256, 0, stream>>>(score, rank0, 4096);
  k_rank_scatter<<<4096 / 256, 256, 0, stream>>>(rank0, perm0, inv0, 4096);
  k_ata_rows<<<2048, 256, 0, stream>>>(rowptr, colidx, perm0, inv0, A1b, dv1, 2048);
  k_xw<1, 0, 1><<<2048 / 64, 256, 0, stream>>>(h0, down_w, dv1, perm0, score, t2, YT, 2048, 128);
  k_gcn_mfma<<<dim3(2048 / 64, 16), 256, 0, stream>>>(A1b, YT, part, 2048, 4096 / 16);
  k_gcn_fin<0, 1><<<2048 / 8, 256, 0, stream>>>(part, t2, dv1, down_b, h1, pool_w + H, score, 2048, 16, 1);

  // ---- level 1 pooling (2048 -> 1024) ----
  k_rank_count<<<dim3(2048 / 256, 2048 / 512), 256, 0, stream>>>(score, rank1, 2048);
  k_rank_scatter<<<2048 / 256, 256, 0, stream>>>(rank1, perm1, inv1, 2048);
  k_ata_mfma_g<<<dim3(16, 16, 4), 256, 0, stream>>>(A1b, perm1, part, 2048, 1024, 512);
  k_ata_fin<4><<<1024, 256, 0, stream>>>(part, A2m, dv2, 1024);
  k_xw<1, 1, 0><<<1024 / 64, 256, 0, stream>>>(h1, down_w + (size_t)H * H, dv2, perm1, score, t2, nullptr, 1024, 128);
  k_gcn_part<<<dim3(1024 / 64, 8), 256, 0, stream>>>(A2m, t2, part, 1024, 128);
  k_gcn_fin<1, 1><<<1024 / 8, 256, 0, stream>>>(part, t2, dv2, down_b + H, h2, pool_w + 2 * H, score, 1024, 8, 1);

  // ---- level 2 pooling (1024 -> 512) ----
  k_rank_count<<<dim3(1024 / 256, 1024 / 512), 256, 0, stream>>>(score, rank2, 1024);
  k_rank_scatter<<<1024 / 256, 256, 0, stream>>>(rank2, perm2, inv2, 1024);
  k_ata_sk_part<<<dim3(8, 8, 8), 256, 0, stream>>>(A2m, perm2, part, 1024, 512, 128);
  k_ata_fin<8><<<512, 128, 0, stream>>>(part, A3, dv3, 512);
  k_xw<1, 1, 0><<<512 / 64, 256, 0, stream>>>(h2, down_w + (size_t)2 * H * H, dv3, perm2, score, t2, nullptr, 512, 128);
  k_gcn_part<<<dim3(512 / 64, 8), 256, 0, stream>>>(A3, t2, part, 512, 64);
  k_gcn_fin<1, 0><<<512 / 8, 256, 0, stream>>>(part, t2, dv3, down_b + 2 * H, h3, nullptr, nullptr, 512, 8, 1);

  // ---- up path ----
  k_xw<2, 1, 0><<<1024 / 64, 256, 0, stream>>>(h2, up_w, dv2, inv2, h3, t2, nullptr, 1024, 128);
  k_gcn_part<<<dim3(1024 / 64, 8), 256, 0, stream>>>(A2m, t2, part, 1024, 128);
  k_gcn_fin<1, 0><<<1024 / 8, 256, 0, stream>>>(part, t2, dv2, up_b, hu, nullptr, nullptr, 1024, 8, 1);

  k_xw<2, 0, 1><<<2048 / 64, 256, 0, stream>>>(h1, up_w + (size_t)H * H, dv1, inv1, hu, t2, YT, 2048, 128);
  k_gcn_mfma<<<dim3(2048 / 64, 16), 256, 0, stream>>>(A1b, YT, part, 2048, 4096 / 16);
  k_gcn_fin<0, 0><<<2048 / 8, 256, 0, stream>>>(part, t2, dv1, up_b + H, hu, nullptr, nullptr, 2048, 16, 1);

  k_xw<2, 0, 0><<<4096 / 64, 256, 0, stream>>>(h0, up_w + (size_t)2 * H * H, dv0, inv0, hu, t2, nullptr, 4096, 128);
  k_spmm_fin<0><<<1024, 256, 0, stream>>>(rowptr, colidx, t2, dv0, up_b + 2 * H, hu, nullptr, nullptr, 4096, 0);

  // ---- pool + head ----
  hipMemsetAsync(g, 0, NG * H * 4, stream);
  k_segsum<<<4096 / 32, 128, 0, stream>>>(hu, batch, g, 4096);
  k_head<<<1, 256, 0, stream>>>(g, lins_w, lins_b, bn_g, bn_b, out_w, out_b, (float*)d_out);
}